// Round 4
// baseline (465.940 us; speedup 1.0000x reference)
//
#include <hip/hip_runtime.h>
#include <hip/hip_bf16.h>

// B=64, C=512, H=W=28, NL=4. All fp32. Per layer:
//   seq = mean_HW(x); (ht,ct)=cell(seq,ht,ct); out_h=cell(seq, ht[0], ct[0]).h
//   x = x*(1+out_h) + depthwise3x3(x)
// Fusions: pool folded into previous update's epilogue; all cell matvecs in one
// kernel (block 0 appends g_h2 tail); ht/ct zero-init folded into cell (first flag).
// update: 16B-aligned LDS tile (stride 28, zero rows top/bottom, guard words for
// column edges) -> ds_write_b128 / ds_read_b128 + ds_read2_b32 instead of scalar ops.

#define HW 784
#define F4 196        // float4 per plane
#define NPLANES 32768 // B*C
#define CC 512
#define BB 64

__device__ __forceinline__ float sigm(float x) { return 1.f / (1.f + __expf(-x)); }

// ---- mean over HW per plane (layer 0 only); one wave per plane ----
__global__ void pool_kernel(const float* __restrict__ x, float* __restrict__ seq) {
    int wave = threadIdx.x >> 6, lane = threadIdx.x & 63;
    int p = blockIdx.x * 4 + wave;
    const float4* b4 = (const float4*)(x + (size_t)p * HW);
    float s = 0.f;
    for (int j = lane; j < F4; j += 64) {
        float4 v = b4[j];
        s += v.x + v.y + v.z + v.w;
    }
    for (int off = 32; off > 0; off >>= 1) s += __shfl_down(s, off, 64);
    if (lane == 0) seq[p] = s * (1.f / 784.f);
}

// ---- all cell math for one layer: hid -> G_i, ht, ct; block 0 also g_h2 ----
__global__ void __launch_bounds__(256) cell_fused_kernel(
        const float* __restrict__ seq,
        const float* __restrict__ w_ih1, const float* __restrict__ b_ih1,
        const float* __restrict__ w_ih2, const float* __restrict__ b_ih2,
        const float* __restrict__ w_hh1, const float* __restrict__ b_hh1,
        const float* __restrict__ w_hh2, const float* __restrict__ b_hh2,
        float* __restrict__ G_i, float* __restrict__ ht, float* __restrict__ ct,
        float* __restrict__ g_h2, int first) {
    __shared__ float s_in[2][CC];   // seq row, ht row
    __shared__ float s_hid[64];     // hid_i[0:32], hid_h[32:64]
    __shared__ float s_g[1536];
    __shared__ float s_h0[CC];      // block 0: new ht row 0
    __shared__ float s_hid2[32];
    int b = blockIdx.x, t = threadIdx.x;  // 256 threads

    for (int k = t; k < CC; k += 256) {
        s_in[0][k] = seq[b * CC + k];
        s_in[1][k] = first ? 0.f : ht[b * CC + k];
    }
    __syncthreads();

    // stage A: hid_{i,h}[j] = relu(b + <in, W1[j,:]>); 64 outputs x 4 lanes
    {
        int o = t >> 2, q = t & 3;
        int which = o >> 5, j = o & 31;
        const float* w = (which ? w_hh1 : w_ih1) + j * CC + q * 128;
        const float* in = s_in[which] + q * 128;
        float acc = 0.f;
        #pragma unroll 8
        for (int k = 0; k < 128; k++) acc += in[k] * w[k];
        acc += __shfl_down(acc, 2, 64);
        acc += __shfl_down(acc, 1, 64);
        if (q == 0) s_hid[o] = fmaxf(acc + (which ? b_hh1 : b_ih1)[j], 0.f);
    }
    __syncthreads();

    // stage B: G_i[b,o] and g = G_i + G_h
    for (int o = t; o < 1536; o += 256) {
        float gi = b_ih2[o], gh = b_hh2[o];
        const float* wi = w_ih2 + o * 32;
        const float* wh = w_hh2 + o * 32;
        #pragma unroll
        for (int k = 0; k < 32; k++) {
            gi += s_hid[k] * wi[k];
            gh += s_hid[32 + k] * wh[k];
        }
        G_i[b * 1536 + o] = gi;
        s_g[o] = gi + gh;
    }
    __syncthreads();

    // stage C: gates -> ct, ht
    for (int c = t; c < CC; c += 256) {
        float cold = first ? 0.f : ct[b * CC + c];
        float nc = sigm(s_g[CC + c]) * cold + sigm(s_g[c]) * tanhf(s_g[2 * CC + c]);
        ct[b * CC + c] = nc;
        float h = sigm(nc);
        ht[b * CC + c] = h;
        s_h0[c] = h;
    }
    if (b != 0) return;  // only block 0 runs the cell-2 hidden path
    __syncthreads();

    // stage D: hid2 = relu(W_hh1 . ht0 + b_hh1); 32 outputs x 8 lanes
    {
        int o = t >> 3, q = t & 7;
        const float* w = w_hh1 + o * CC + q * 64;
        const float* in = s_h0 + q * 64;
        float acc = 0.f;
        #pragma unroll 8
        for (int k = 0; k < 64; k++) acc += in[k] * w[k];
        acc += __shfl_down(acc, 4, 64);
        acc += __shfl_down(acc, 2, 64);
        acc += __shfl_down(acc, 1, 64);
        if (q == 0) s_hid2[o] = fmaxf(acc + b_hh1[o], 0.f);
    }
    __syncthreads();

    // stage E: g_h2 = W_hh2 . hid2 + b_hh2
    for (int o = t; o < 1536; o += 256) {
        float acc = b_hh2[o];
        const float* wh = w_hh2 + o * 32;
        #pragma unroll
        for (int k = 0; k < 32; k++) acc += s_hid2[k] * wh[k];
        g_h2[o] = acc;
    }
}

// ---- y = x*(1+oh) + dw3x3(x); fused mean(y) -> seq_next. One block per plane ----
// LDS tile: 30 rows x 28 cols, stride 28 floats (16B aligned rows), rows 0/29 zero.
// Column edges handled in registers; guard words before/after tile keep OOB LDS
// reads harmless (values discarded by selects).
__global__ void __launch_bounds__(256) update_kernel(
        const float* __restrict__ x, float* __restrict__ y,
        const float* __restrict__ G_i, const float* __restrict__ g_h2,
        const float* __restrict__ ct0, const float* __restrict__ dwk,
        float* __restrict__ seq_next) {
    __shared__ float tile_full[848];   // [0..3] guard, [4..843] tile, [844..847] guard
    __shared__ float s_w[9];
    __shared__ float s_oh;
    __shared__ float s_part[256];
    float* tile = tile_full + 4;       // 16B aligned
    int p = blockIdx.x;
    int b = p >> 9, c = p & 511;
    int t = threadIdx.x;               // 196 fill/compute lanes + helpers

    int py = t / 7, px4 = t - py * 7;  // t<196: row, float4-col
    if (t < F4) {
        float4 v = ((const float4*)(x + (size_t)p * HW))[t];
        *(float4*)&tile[(py + 1) * 28 + px4 * 4] = v;
    } else if (t < 210) {
        int idx = t - F4;              // 0..13 -> zero rows 0 and 29
        int row = (idx < 7) ? 0 : 29;
        int c4 = (idx < 7) ? idx : idx - 7;
        *(float4*)&tile[row * 28 + c4 * 4] = make_float4(0.f, 0.f, 0.f, 0.f);
    }
    if (t < 9) s_w[t] = dwk[c * 9 + t];
    if (t == 255) {
        const float* g = G_i + b * 1536;
        float ig = g[c] + g_h2[c];
        float fg = g[CC + c] + g_h2[CC + c];
        float cg = g[2 * CC + c] + g_h2[2 * CC + c];
        float nc = sigm(fg) * ct0[c] + sigm(ig) * tanhf(cg);
        s_oh = sigm(nc);
    }
    __syncthreads();

    float sum = 0.f;
    if (t < F4) {
        float oh1 = 1.f + s_oh;
        float a0 = 0.f, a1 = 0.f, a2 = 0.f, a3 = 0.f;
        float c0 = 0.f, c1 = 0.f, c2 = 0.f, c3 = 0.f;
        #pragma unroll
        for (int q = 0; q < 3; q++) {
            int base = (py + q) * 28 + px4 * 4;
            float4 m = *(const float4*)&tile[base];
            float lraw = tile[base - 1];
            float rraw = tile[base + 4];
            float l = (px4 == 0) ? 0.f : lraw;
            float r = (px4 == 6) ? 0.f : rraw;
            float w0 = s_w[q * 3], w1 = s_w[q * 3 + 1], w2 = s_w[q * 3 + 2];
            a0 += l   * w0 + m.x * w1 + m.y * w2;
            a1 += m.x * w0 + m.y * w1 + m.z * w2;
            a2 += m.y * w0 + m.z * w1 + m.w * w2;
            a3 += m.z * w0 + m.w * w1 + r   * w2;
            if (q == 1) { c0 = m.x; c1 = m.y; c2 = m.z; c3 = m.w; }
        }
        float y0 = a0 + c0 * oh1;
        float y1 = a1 + c1 * oh1;
        float y2 = a2 + c2 * oh1;
        float y3 = a3 + c3 * oh1;
        ((float4*)(y + (size_t)p * HW))[t] = make_float4(y0, y1, y2, y3);
        sum = y0 + y1 + y2 + y3;
    }
    s_part[t] = sum;
    __syncthreads();
    if (t < 64) {
        float s = s_part[t] + s_part[t + 64] + s_part[t + 128] + s_part[t + 192];
        for (int off = 32; off > 0; off >>= 1) s += __shfl_down(s, off, 64);
        if (t == 0) seq_next[p] = s * (1.f / 784.f);
    }
}

extern "C" void kernel_launch(void* const* d_in, const int* in_sizes, int n_in,
                              void* d_out, int out_size, void* d_ws, size_t ws_size,
                              hipStream_t stream) {
    const float* x_in  = (const float*)d_in[0];
    const float* w_ih1 = (const float*)d_in[1];
    const float* b_ih1 = (const float*)d_in[2];
    const float* w_ih2 = (const float*)d_in[3];
    const float* b_ih2 = (const float*)d_in[4];
    const float* w_hh1 = (const float*)d_in[5];
    const float* b_hh1 = (const float*)d_in[6];
    const float* w_hh2 = (const float*)d_in[7];
    const float* b_hh2 = (const float*)d_in[8];
    const float* dwk   = (const float*)d_in[9];
    float* out = (float*)d_out;
    char* ws = (char*)d_ws;

    float* seq  = (float*)(ws + 0);        // 64*512  = 131072 B
    float* G_i  = (float*)(ws + 131072);   // 64*1536 = 393216 B
    float* ht   = (float*)(ws + 524288);   // 64*512  = 131072 B
    float* ct   = (float*)(ws + 655360);   // 64*512  = 131072 B
    float* g_h2 = (float*)(ws + 786432);   // 1536    = 6144 B

    pool_kernel<<<NPLANES / 4, 256, 0, stream>>>(x_in, seq);

    for (int layer = 0; layer < 4; layer++) {
        const float* xcur = (layer == 0) ? x_in : out;
        cell_fused_kernel<<<BB, 256, 0, stream>>>(seq, w_ih1, b_ih1, w_ih2, b_ih2,
                                                  w_hh1, b_hh1, w_hh2, b_hh2,
                                                  G_i, ht, ct, g_h2, layer == 0);
        update_kernel<<<NPLANES, 256, 0, stream>>>(xcur, out, G_i, g_h2, ct, dwk, seq);
    }
}